// Round 1
// baseline (637.949 us; speedup 1.0000x reference)
//
#include <hip/hip_runtime.h>
#include <hip/hip_bf16.h>

// Local-window attention, B=32 S=1024(16x64) H=8 D=48 C=384, window 7x11.
// R1: correctness-first. K1: f32 GEMM -> qkv scatter (bf16, [B,H,S,D], q scaled).
// K2: flash-style local attn, 1 wave per (b,h,img_row), lane = query column.
// K3: f32 GEMM + bias -> d_out.

typedef __attribute__((ext_vector_type(8))) unsigned short ushort8;

__device__ __forceinline__ float bf2f(unsigned short u) {
  union { unsigned int i; float f; } x;
  x.i = ((unsigned int)u) << 16;
  return x.f;
}

// ---------------- GEMM: 128x128 tile, 8x8 micro, f32 accum ----------------
// MODE 0: C = A[32768,384] @ B[384,N] ; scatter to q/k/v bf16 [B,H,S,D], q scaled
// MODE 1: C = A @ B + bias ; f32 coalesced store
template <int MODE>
__global__ __launch_bounds__(256) void gemm_k(
    const float* __restrict__ A, const float* __restrict__ Bm, int N,
    const float* __restrict__ bias, float* __restrict__ outf,
    __hip_bfloat16* __restrict__ qws, __hip_bfloat16* __restrict__ kws,
    __hip_bfloat16* __restrict__ vws)
{
  const int K = 384;
  __shared__ float As[16][128];  // As[kk][m]
  __shared__ float Bs[16][128];  // Bs[kk][n]
  const int tid = threadIdx.x;
  const int tr = tid >> 4, tc = tid & 15;
  const int m0 = blockIdx.x * 128, n0 = blockIdx.y * 128;
  const int lam = tid >> 1, lak = (tid & 1) * 8;   // A loader: row, k-offset
  const int lbk = tid >> 4, lbn = (tid & 15) * 8;  // B loader: k-row, n-offset

  float acc[8][8] = {};

  for (int k0 = 0; k0 < K; k0 += 16) {
    const float4 a0 = *reinterpret_cast<const float4*>(&A[(size_t)(m0 + lam) * K + k0 + lak]);
    const float4 a1 = *reinterpret_cast<const float4*>(&A[(size_t)(m0 + lam) * K + k0 + lak + 4]);
    const float4 b0 = *reinterpret_cast<const float4*>(&Bm[(size_t)(k0 + lbk) * N + n0 + lbn]);
    const float4 b1 = *reinterpret_cast<const float4*>(&Bm[(size_t)(k0 + lbk) * N + n0 + lbn + 4]);
    __syncthreads();  // previous iteration's readers done
    As[lak + 0][lam] = a0.x; As[lak + 1][lam] = a0.y;
    As[lak + 2][lam] = a0.z; As[lak + 3][lam] = a0.w;
    As[lak + 4][lam] = a1.x; As[lak + 5][lam] = a1.y;
    As[lak + 6][lam] = a1.z; As[lak + 7][lam] = a1.w;
    *reinterpret_cast<float4*>(&Bs[lbk][lbn])     = b0;
    *reinterpret_cast<float4*>(&Bs[lbk][lbn + 4]) = b1;
    __syncthreads();
    #pragma unroll
    for (int kx = 0; kx < 16; ++kx) {
      float a[8], b[8];
      *reinterpret_cast<float4*>(&a[0]) = *reinterpret_cast<const float4*>(&As[kx][tr * 8]);
      *reinterpret_cast<float4*>(&a[4]) = *reinterpret_cast<const float4*>(&As[kx][tr * 8 + 4]);
      *reinterpret_cast<float4*>(&b[0]) = *reinterpret_cast<const float4*>(&Bs[kx][tc * 8]);
      *reinterpret_cast<float4*>(&b[4]) = *reinterpret_cast<const float4*>(&Bs[kx][tc * 8 + 4]);
      #pragma unroll
      for (int u = 0; u < 8; ++u)
        #pragma unroll
        for (int w = 0; w < 8; ++w)
          acc[u][w] = fmaf(a[u], b[w], acc[u][w]);
    }
  }

  if (MODE == 0) {
    const float QSCALE = 0.14433756729740643f;  // 1/sqrt(48)
    #pragma unroll
    for (int u = 0; u < 8; ++u) {
      const int r = m0 + tr * 8 + u;
      const int b = r >> 10, s = r & 1023;
      #pragma unroll
      for (int w = 0; w < 8; ++w) {
        const int c = n0 + tc * 8 + w;
        const int which = c / 384;
        const int rem = c - which * 384;
        const int h = rem / 48, d = rem - h * 48;
        const size_t off = (((size_t)(b * 8 + h)) * 1024 + s) * 48 + d;
        const float v = acc[u][w];
        if (which == 0)      qws[off] = __float2bfloat16(v * QSCALE);
        else if (which == 1) kws[off] = __float2bfloat16(v);
        else                 vws[off] = __float2bfloat16(v);
      }
    }
  } else {
    float bv[8];
    #pragma unroll
    for (int w = 0; w < 8; ++w) bv[w] = bias[n0 + tc * 8 + w];
    #pragma unroll
    for (int u = 0; u < 8; ++u) {
      const size_t r = m0 + tr * 8 + u;
      float* orow = outf + r * 384 + n0 + tc * 8;
      *reinterpret_cast<float4*>(orow) =
          make_float4(acc[u][0] + bv[0], acc[u][1] + bv[1], acc[u][2] + bv[2], acc[u][3] + bv[3]);
      *reinterpret_cast<float4*>(orow + 4) =
          make_float4(acc[u][4] + bv[4], acc[u][5] + bv[5], acc[u][6] + bv[6], acc[u][7] + bv[7]);
    }
  }
}

// ---------------- local attention ----------------
// grid = B*H*16 blocks of 64 threads (1 wave). lane j = query column.
// Streams the 7 valid key image-rows through LDS; lane-local online softmax.
__global__ __launch_bounds__(64) void attn_local(
    const __hip_bfloat16* __restrict__ qws,
    const __hip_bfloat16* __restrict__ kws,
    const __hip_bfloat16* __restrict__ vws,
    float* __restrict__ attn_out)  // [B*S, 384] f32
{
  __shared__ float ksm[64][52];  // stride 52: float4-aligned, conflict-spread
  __shared__ float vsm[64][52];

  const int blk = blockIdx.x;
  const int i = blk & 15;
  const int h = (blk >> 4) & 7;
  const int b = blk >> 7;
  const int j = threadIdx.x;  // query column 0..63
  const size_t bh = ((size_t)b * 8 + h) * 1024;

  // q into registers (48 f32), already scaled by 1/sqrt(D) in K1
  float q[48];
  {
    const ushort8* qp = reinterpret_cast<const ushort8*>(qws + (bh + (size_t)i * 64 + j) * 48);
    #pragma unroll
    for (int u = 0; u < 6; ++u) {
      const ushort8 t = qp[u];
      #pragma unroll
      for (int w = 0; w < 8; ++w) q[u * 8 + w] = bf2f(t[w]);
    }
  }

  float m = -INFINITY, l = 0.f;
  float o[48];
  #pragma unroll
  for (int d = 0; d < 48; ++d) o[d] = 0.f;

  const int ki0 = (i - 3 < 0) ? 0 : i - 3;
  const int ki1 = (i + 3 > 15) ? 15 : i + 3;

  for (int ki = ki0; ki <= ki1; ++ki) {
    __syncthreads();
    // lane j stages key/value (ki*64 + j): 48 bf16 -> f32 LDS row j
    {
      const ushort8* kp = reinterpret_cast<const ushort8*>(kws + (bh + (size_t)ki * 64 + j) * 48);
      const ushort8* vp = reinterpret_cast<const ushort8*>(vws + (bh + (size_t)ki * 64 + j) * 48);
      #pragma unroll
      for (int u = 0; u < 6; ++u) {
        const ushort8 tk = kp[u];
        const ushort8 tv = vp[u];
        *reinterpret_cast<float4*>(&ksm[j][u * 8]) =
            make_float4(bf2f(tk[0]), bf2f(tk[1]), bf2f(tk[2]), bf2f(tk[3]));
        *reinterpret_cast<float4*>(&ksm[j][u * 8 + 4]) =
            make_float4(bf2f(tk[4]), bf2f(tk[5]), bf2f(tk[6]), bf2f(tk[7]));
        *reinterpret_cast<float4*>(&vsm[j][u * 8]) =
            make_float4(bf2f(tv[0]), bf2f(tv[1]), bf2f(tv[2]), bf2f(tv[3]));
        *reinterpret_cast<float4*>(&vsm[j][u * 8 + 4]) =
            make_float4(bf2f(tv[4]), bf2f(tv[5]), bf2f(tv[6]), bf2f(tv[7]));
      }
    }
    __syncthreads();

    // scores for the 11 columns in [j-5, j+5]
    float sc[11];
    float rowmax = -INFINITY;
    #pragma unroll
    for (int n = 0; n < 11; ++n) {
      const int kj = j - 5 + n;
      const bool valid = ((unsigned)kj < 64u);
      const int kjc = valid ? kj : j;
      const float* kr = &ksm[kjc][0];
      float accd = 0.f;
      #pragma unroll
      for (int u = 0; u < 12; ++u) {
        const float4 kv = *reinterpret_cast<const float4*>(kr + 4 * u);
        accd = fmaf(q[4 * u + 0], kv.x, accd);
        accd = fmaf(q[4 * u + 1], kv.y, accd);
        accd = fmaf(q[4 * u + 2], kv.z, accd);
        accd = fmaf(q[4 * u + 3], kv.w, accd);
      }
      sc[n] = valid ? accd : -INFINITY;
      rowmax = fmaxf(rowmax, sc[n]);
    }

    const float mnew = fmaxf(m, rowmax);           // finite (own column always valid)
    const float corr = __expf(m - mnew);           // exp(-inf)=0 on first row
    float p[11], psum = 0.f;
    #pragma unroll
    for (int n = 0; n < 11; ++n) { p[n] = __expf(sc[n] - mnew); psum += p[n]; }
    l = l * corr + psum;
    m = mnew;
    #pragma unroll
    for (int d = 0; d < 48; ++d) o[d] *= corr;
    #pragma unroll
    for (int n = 0; n < 11; ++n) {
      const int kj = j - 5 + n;
      const int kjc = ((unsigned)kj < 64u) ? kj : j;  // p[n]==0 when clamped
      const float pn = p[n];
      const float* vr = &vsm[kjc][0];
      #pragma unroll
      for (int u = 0; u < 12; ++u) {
        const float4 vv = *reinterpret_cast<const float4*>(vr + 4 * u);
        o[4 * u + 0] = fmaf(pn, vv.x, o[4 * u + 0]);
        o[4 * u + 1] = fmaf(pn, vv.y, o[4 * u + 1]);
        o[4 * u + 2] = fmaf(pn, vv.z, o[4 * u + 2]);
        o[4 * u + 3] = fmaf(pn, vv.w, o[4 * u + 3]);
      }
    }
  }

  const float inv = 1.0f / l;
  float* op = attn_out + ((size_t)b * 1024 + (size_t)i * 64 + j) * 384 + h * 48;
  #pragma unroll
  for (int u = 0; u < 12; ++u) {
    *reinterpret_cast<float4*>(op + 4 * u) =
        make_float4(o[4 * u] * inv, o[4 * u + 1] * inv, o[4 * u + 2] * inv, o[4 * u + 3] * inv);
  }
}

extern "C" void kernel_launch(void* const* d_in, const int* in_sizes, int n_in,
                              void* d_out, int out_size, void* d_ws, size_t ws_size,
                              hipStream_t stream) {
  const float* x      = (const float*)d_in[0];
  const float* w_qkv  = (const float*)d_in[1];
  const float* w_proj = (const float*)d_in[2];
  const float* b_proj = (const float*)d_in[3];
  // d_in[4] (mask) unused: window is analytic (|di|<=3, |dj|<=5)

  const size_t QKV_ELEMS = (size_t)32 * 8 * 1024 * 48;  // per tensor
  __hip_bfloat16* qws = (__hip_bfloat16*)d_ws;
  __hip_bfloat16* kws = qws + QKV_ELEMS;
  __hip_bfloat16* vws = kws + QKV_ELEMS;
  float* attn_out = (float*)(vws + QKV_ELEMS);  // 75.5MB offset, 16B aligned
  float* out = (float*)d_out;

  // K1: qkv = x @ w_qkv  (M=32768, K=384, N=1152), scatter to [B,H,S,D] bf16
  gemm_k<0><<<dim3(256, 9), 256, 0, stream>>>(x, w_qkv, 1152, nullptr, nullptr,
                                              qws, kws, vws);
  // K2: local attention -> attn_out [B*S, 384] f32
  attn_local<<<dim3(4096), 64, 0, stream>>>(qws, kws, vws, attn_out);
  // K3: out = attn_out @ w_proj + b_proj  (N=384)
  gemm_k<1><<<dim3(256, 3), 256, 0, stream>>>(attn_out, w_proj, 384, b_proj, out,
                                              nullptr, nullptr, nullptr);
}

// Round 2
// 225.105 us; speedup vs baseline: 2.8340x; 2.8340x over previous
//
#include <hip/hip_runtime.h>
#include <hip/hip_bf16.h>

// Local-window attention, B=32 S=1024(16x64) H=8 D=48 C=384, window 7x11.
// R2: bf16 MFMA GEMMs (m97 structure) + unchanged flash-local attention.
//  K0a: x f32 -> bf16            K0b/K0c: w_qkv/w_proj transpose->bf16 [N][K]
//  K1: MFMA GEMM -> q/k/v bf16 [B,H,S,D] (q pre-scaled)
//  K2: local attention (1 wave per (b,h,row)), writes bf16 attn_out
//  K3: MFMA GEMM + bias -> f32 d_out

typedef __attribute__((ext_vector_type(8))) unsigned short ushort8;
typedef __attribute__((ext_vector_type(4))) unsigned short ushort4v;
typedef __attribute__((ext_vector_type(8))) short short8v;
typedef __attribute__((ext_vector_type(4))) float floatx4;

__device__ __forceinline__ float bf2f(unsigned short u) {
  union { unsigned int i; float f; } x;
  x.i = ((unsigned int)u) << 16;
  return x.f;
}

__device__ __forceinline__ unsigned short f2bu(float f) {
  union { float f; unsigned int i; } x;
  x.f = f;
  unsigned int lsb = (x.i >> 16) & 1u;
  x.i += 0x7FFFu + lsb;  // RNE
  return (unsigned short)(x.i >> 16);
}

__device__ __forceinline__ void gload_lds16(const void* g, void* l) {
  __builtin_amdgcn_global_load_lds(
      (const __attribute__((address_space(1))) unsigned int*)g,
      (__attribute__((address_space(3))) unsigned int*)l, 16, 0, 0);
}

// ---------------- K0a: f32 -> bf16 ----------------
__global__ __launch_bounds__(256) void cvt_f32_bf16(
    const float4* __restrict__ in, ushort4v* __restrict__ out, int n4) {
  const int i = blockIdx.x * 256 + threadIdx.x;
  if (i < n4) {
    const float4 v = in[i];
    ushort4v o;
    o[0] = f2bu(v.x); o[1] = f2bu(v.y); o[2] = f2bu(v.z); o[3] = f2bu(v.w);
    out[i] = o;
  }
}

// ---------------- K0b/c: transpose f32 [R][C] -> bf16 [C][R] ----------------
__global__ __launch_bounds__(256) void transpose_cvt(
    const float* __restrict__ in, unsigned short* __restrict__ out, int R, int C) {
  __shared__ float t[32][33];
  const int c0 = blockIdx.x * 32, r0 = blockIdx.y * 32;
  const int tx = threadIdx.x, ty = threadIdx.y;
  #pragma unroll
  for (int rr = ty; rr < 32; rr += 8) t[rr][tx] = in[(size_t)(r0 + rr) * C + c0 + tx];
  __syncthreads();
  #pragma unroll
  for (int rr = ty; rr < 32; rr += 8)
    out[(size_t)(c0 + rr) * R + r0 + tx] = f2bu(t[tx][rr]);
}

// ---------------- MFMA GEMM: C[M,N] = A[M,384] * Bt[N,384]^T ----------------
// 128x128 tile, BK=32, 4 waves (2x2), wave = 64x64 via 4x4 mfma_16x16x32_bf16.
// LDS tiles [128 rows][64 B], row r's four 16B k-slots XOR-swizzled by (r&3)<<4
// on BOTH the global source (staging) and the ds_read address (rule #21).
// MODE 0: scatter to q/k/v bf16 [B,H,S,D], q scaled. MODE 1: f32 out + bias.
template <int MODE>
__global__ __launch_bounds__(256, 2) void gemm_mfma(
    const unsigned short* __restrict__ A,   // [M][384] bf16
    const unsigned short* __restrict__ Bt,  // [N][384] bf16 (= B^T)
    const float* __restrict__ bias, float* __restrict__ outf,
    unsigned short* __restrict__ qws, unsigned short* __restrict__ kws,
    unsigned short* __restrict__ vws)
{
  __shared__ unsigned short As[128 * 32];
  __shared__ unsigned short Bs[128 * 32];
  const int tid = threadIdx.x;
  const int lane = tid & 63, w = tid >> 6;
  const int wm = w & 1, wn = w >> 1;
  const int n0 = blockIdx.x * 128;  // grid.x = n-tiles (A-panel reuse adjacency)
  const int m0 = blockIdx.y * 128;

  floatx4 acc[4][4];
  #pragma unroll
  for (int mi = 0; mi < 4; ++mi)
    #pragma unroll
    for (int ni = 0; ni < 4; ++ni)
      acc[mi][ni] = (floatx4){0.f, 0.f, 0.f, 0.f};

  const int srow = w * 16 + (lane >> 2);  // staging row within 64-row half
  const int kslot16 = (lane & 3) * 16;    // 16B k-slot byte

  for (int k0 = 0; k0 < 384; k0 += 32) {
    __syncthreads();
    #pragma unroll
    for (int c = 0; c < 2; ++c) {
      const int r = c * 64 + srow;
      const int kb = kslot16 ^ ((r & 3) << 4);  // pre-swizzled global source
      gload_lds16((const char*)A + (size_t)(m0 + r) * 768 + k0 * 2 + kb,
                  (char*)As + c * 4096 + w * 1024);
      gload_lds16((const char*)Bt + (size_t)(n0 + r) * 768 + k0 * 2 + kb,
                  (char*)Bs + c * 4096 + w * 1024);
    }
    __syncthreads();  // drains vmcnt(0) -> tiles complete

    short8v a[4], b[4];
    const int kgb = (lane >> 4) * 16;  // k-group byte offset (8 bf16)
    #pragma unroll
    for (int mi = 0; mi < 4; ++mi) {
      const int r = wm * 64 + mi * 16 + (lane & 15);
      a[mi] = *reinterpret_cast<const short8v*>(
          (const char*)As + r * 64 + (kgb ^ ((r & 3) << 4)));
    }
    #pragma unroll
    for (int ni = 0; ni < 4; ++ni) {
      const int r = wn * 64 + ni * 16 + (lane & 15);
      b[ni] = *reinterpret_cast<const short8v*>(
          (const char*)Bs + r * 64 + (kgb ^ ((r & 3) << 4)));
    }
    #pragma unroll
    for (int mi = 0; mi < 4; ++mi)
      #pragma unroll
      for (int ni = 0; ni < 4; ++ni)
        acc[mi][ni] = __builtin_amdgcn_mfma_f32_16x16x32_bf16(
            a[mi], b[ni], acc[mi][ni], 0, 0, 0);
  }

  const int col_l = lane & 15;
  const int row_l = (lane >> 4) * 4;

  if (MODE == 0) {
    const float QSCALE = 0.14433756729740643f;  // 1/sqrt(48)
    #pragma unroll
    for (int ni = 0; ni < 4; ++ni) {
      const int cg = n0 + wn * 64 + ni * 16 + col_l;
      const int which = cg / 384;
      const int rem = cg - which * 384;
      const int h = rem / 48;
      const int d = rem - h * 48;
      unsigned short* dst = (which == 0) ? qws : (which == 1) ? kws : vws;
      const float scale = (which == 0) ? QSCALE : 1.f;
      #pragma unroll
      for (int mi = 0; mi < 4; ++mi) {
        #pragma unroll
        for (int reg = 0; reg < 4; ++reg) {
          const int r = m0 + wm * 64 + mi * 16 + row_l + reg;
          const int bb = r >> 10, s = r & 1023;
          dst[(((size_t)(bb * 8 + h)) * 1024 + s) * 48 + d] =
              f2bu(acc[mi][ni][reg] * scale);
        }
      }
    }
  } else {
    #pragma unroll
    for (int ni = 0; ni < 4; ++ni) {
      const int cg = n0 + wn * 64 + ni * 16 + col_l;
      const float bv = bias[cg];
      #pragma unroll
      for (int mi = 0; mi < 4; ++mi) {
        #pragma unroll
        for (int reg = 0; reg < 4; ++reg) {
          const int r = m0 + wm * 64 + mi * 16 + row_l + reg;
          outf[(size_t)r * 384 + cg] = acc[mi][ni][reg] + bv;
        }
      }
    }
  }
}

// ---------------- K2: local attention (unchanged math, bf16 out) ----------------
__global__ __launch_bounds__(64) void attn_local(
    const unsigned short* __restrict__ qws,
    const unsigned short* __restrict__ kws,
    const unsigned short* __restrict__ vws,
    unsigned short* __restrict__ attn_out)  // [B*S, 384] bf16
{
  __shared__ float ksm[64][52];
  __shared__ float vsm[64][52];

  const int blk = blockIdx.x;
  const int i = blk & 15;
  const int h = (blk >> 4) & 7;
  const int b = blk >> 7;
  const int j = threadIdx.x;
  const size_t bh = ((size_t)b * 8 + h) * 1024;

  float q[48];
  {
    const ushort8* qp = reinterpret_cast<const ushort8*>(qws + (bh + (size_t)i * 64 + j) * 48);
    #pragma unroll
    for (int u = 0; u < 6; ++u) {
      const ushort8 t = qp[u];
      #pragma unroll
      for (int w = 0; w < 8; ++w) q[u * 8 + w] = bf2f(t[w]);
    }
  }

  float m = -INFINITY, l = 0.f;
  float o[48];
  #pragma unroll
  for (int d = 0; d < 48; ++d) o[d] = 0.f;

  const int ki0 = (i - 3 < 0) ? 0 : i - 3;
  const int ki1 = (i + 3 > 15) ? 15 : i + 3;

  for (int ki = ki0; ki <= ki1; ++ki) {
    __syncthreads();
    {
      const ushort8* kp = reinterpret_cast<const ushort8*>(kws + (bh + (size_t)ki * 64 + j) * 48);
      const ushort8* vp = reinterpret_cast<const ushort8*>(vws + (bh + (size_t)ki * 64 + j) * 48);
      #pragma unroll
      for (int u = 0; u < 6; ++u) {
        const ushort8 tk = kp[u];
        const ushort8 tv = vp[u];
        *reinterpret_cast<float4*>(&ksm[j][u * 8]) =
            make_float4(bf2f(tk[0]), bf2f(tk[1]), bf2f(tk[2]), bf2f(tk[3]));
        *reinterpret_cast<float4*>(&ksm[j][u * 8 + 4]) =
            make_float4(bf2f(tk[4]), bf2f(tk[5]), bf2f(tk[6]), bf2f(tk[7]));
        *reinterpret_cast<float4*>(&vsm[j][u * 8]) =
            make_float4(bf2f(tv[0]), bf2f(tv[1]), bf2f(tv[2]), bf2f(tv[3]));
        *reinterpret_cast<float4*>(&vsm[j][u * 8 + 4]) =
            make_float4(bf2f(tv[4]), bf2f(tv[5]), bf2f(tv[6]), bf2f(tv[7]));
      }
    }
    __syncthreads();

    float sc[11];
    float rowmax = -INFINITY;
    #pragma unroll
    for (int n = 0; n < 11; ++n) {
      const int kj = j - 5 + n;
      const bool valid = ((unsigned)kj < 64u);
      const int kjc = valid ? kj : j;
      const float* kr = &ksm[kjc][0];
      float accd = 0.f;
      #pragma unroll
      for (int u = 0; u < 12; ++u) {
        const float4 kv = *reinterpret_cast<const float4*>(kr + 4 * u);
        accd = fmaf(q[4 * u + 0], kv.x, accd);
        accd = fmaf(q[4 * u + 1], kv.y, accd);
        accd = fmaf(q[4 * u + 2], kv.z, accd);
        accd = fmaf(q[4 * u + 3], kv.w, accd);
      }
      sc[n] = valid ? accd : -INFINITY;
      rowmax = fmaxf(rowmax, sc[n]);
    }

    const float mnew = fmaxf(m, rowmax);
    const float corr = __expf(m - mnew);
    float p[11], psum = 0.f;
    #pragma unroll
    for (int n = 0; n < 11; ++n) { p[n] = __expf(sc[n] - mnew); psum += p[n]; }
    l = l * corr + psum;
    m = mnew;
    #pragma unroll
    for (int d = 0; d < 48; ++d) o[d] *= corr;
    #pragma unroll
    for (int n = 0; n < 11; ++n) {
      const int kj = j - 5 + n;
      const int kjc = ((unsigned)kj < 64u) ? kj : j;
      const float pn = p[n];
      const float* vr = &vsm[kjc][0];
      #pragma unroll
      for (int u = 0; u < 12; ++u) {
        const float4 vv = *reinterpret_cast<const float4*>(vr + 4 * u);
        o[4 * u + 0] = fmaf(pn, vv.x, o[4 * u + 0]);
        o[4 * u + 1] = fmaf(pn, vv.y, o[4 * u + 1]);
        o[4 * u + 2] = fmaf(pn, vv.z, o[4 * u + 2]);
        o[4 * u + 3] = fmaf(pn, vv.w, o[4 * u + 3]);
      }
    }
  }

  const float inv = 1.0f / l;
  unsigned short* op = attn_out + ((size_t)b * 1024 + (size_t)i * 64 + j) * 384 + h * 48;
  #pragma unroll
  for (int u = 0; u < 6; ++u) {
    ushort8 pk;
    #pragma unroll
    for (int w2 = 0; w2 < 8; ++w2) pk[w2] = f2bu(o[u * 8 + w2] * inv);
    *reinterpret_cast<ushort8*>(op + u * 8) = pk;
  }
}

extern "C" void kernel_launch(void* const* d_in, const int* in_sizes, int n_in,
                              void* d_out, int out_size, void* d_ws, size_t ws_size,
                              hipStream_t stream) {
  const float* x      = (const float*)d_in[0];
  const float* w_qkv  = (const float*)d_in[1];
  const float* w_proj = (const float*)d_in[2];
  const float* b_proj = (const float*)d_in[3];
  // d_in[4] (mask) unused: window is analytic (|di|<=3, |dj|<=5)

  const size_t T = 25165824;  // 32768*384*2 bytes
  char* ws = (char*)d_ws;
  unsigned short* xb    = (unsigned short*)ws;            // aliased with attn_out
  unsigned short* qws   = (unsigned short*)(ws + T);
  unsigned short* kws   = (unsigned short*)(ws + 2 * T);
  unsigned short* vws   = (unsigned short*)(ws + 3 * T);
  unsigned short* wqkvT = (unsigned short*)(ws + 4 * T);
  unsigned short* wpT   = (unsigned short*)(ws + 4 * T + 884736);
  unsigned short* attn_out = xb;  // xb dead after K1
  float* out = (float*)d_out;

  // K0: conversions
  cvt_f32_bf16<<<12288, 256, 0, stream>>>((const float4*)x, (ushort4v*)xb, 3145728);
  transpose_cvt<<<dim3(36, 12), dim3(32, 8), 0, stream>>>(w_qkv, wqkvT, 384, 1152);
  transpose_cvt<<<dim3(12, 12), dim3(32, 8), 0, stream>>>(w_proj, wpT, 384, 384);

  // K1: qkv GEMM (M=32768, K=384, N=1152) -> scatter bf16 [B,H,S,D]
  gemm_mfma<0><<<dim3(9, 256), 256, 0, stream>>>(xb, wqkvT, nullptr, nullptr,
                                                 qws, kws, vws);
  // K2: local attention -> attn_out bf16 [B*S, 384]
  attn_local<<<dim3(4096), 64, 0, stream>>>(qws, kws, vws, attn_out);
  // K3: out = attn_out @ w_proj + bias (N=384), f32 out
  gemm_mfma<1><<<dim3(3, 256), 256, 0, stream>>>(attn_out, wpT, b_proj, out,
                                                 nullptr, nullptr, nullptr);
}